// Round 15
// baseline (317.685 us; speedup 1.0000x reference)
//
#include <hip/hip_runtime.h>

#define NN     256
#define NF     127
#define DIM    128
#define NH     8
#define DH     64
#define INNER  512
#define DEPTH  6
#define NB     512
#define ATTN_SCALE 0.125f
#define LN_EPS 1e-5f

typedef _Float16 f16;
union H8 { uint4 u; f16 h[8]; };

#define FMA4(A_, S_, V_) { A_.x=fmaf(S_,(V_).x,A_.x); A_.y=fmaf(S_,(V_).y,A_.y); \
                           A_.z=fmaf(S_,(V_).z,A_.z); A_.w=fmaf(S_,(V_).w,A_.w); }

__device__ __forceinline__ float wred_sum(float v){
#pragma unroll
  for(int o=32;o;o>>=1) v += __shfl_xor(v,o);
  return v;
}
__device__ __forceinline__ float wred_max(float v){
#pragma unroll
  for(int o=32;o;o>>=1) v = fmaxf(v,__shfl_xor(v,o));
  return v;
}
__device__ __forceinline__ float2 wred_sum2(float a, float b){
#pragma unroll
  for(int o=32;o;o>>=1){ a += __shfl_xor(a,o); b += __shfl_xor(b,o); }
  return make_float2(a,b);
}

// In-wave LayerNorm of a 128-dim row held as (n0,n1) = dims (l, l+64) per lane.
__device__ __forceinline__ void ln_wave(float n0, float n1,
                                        const float* g, const float* b, int l,
                                        float& x0, float& x1){
  float2 sv = wred_sum2(n0+n1, n0*n0+n1*n1);
  float m  = sv.x*(1.f/DIM);
  float var = sv.y*(1.f/DIM) - m*m;
  float rs = rsqrtf(var + LN_EPS);
  x0 = (n0-m)*rs*g[l]    + b[l];
  x1 = (n1-m)*rs*g[64+l] + b[64+l];
}

// In-wave gated residual. No barriers.
__device__ __forceinline__ void gate_wave(float o0, float o1, float& n0, float& n1,
                                          const float* Wg, int l){
  float gv = o0*Wg[l]    + n0*Wg[DIM+l]    + (o0-n0)*Wg[2*DIM+l]
           + o1*Wg[64+l] + n1*Wg[DIM+64+l] + (o1-n1)*Wg[2*DIM+64+l];
  gv = wred_sum(gv);
  float gate = 1.f/(1.f + expf(-gv));
  n0 = o0*gate + n0*(1.f-gate);
  n1 = o1*gate + n1*(1.f-gate);
}

// ---- fp16-weight matvec partials ----
// x[128] @ W[128][512]h -> SC[fg*512+c], fg in [0,8)
__device__ __forceinline__ void mvp128_512h(const float* __restrict__ xin,
                                            const f16* __restrict__ W,
                                            float* __restrict__ SC, int t){
  const int cg8 = (t&63)<<3, fg = t>>6, f0 = fg<<4;
  const f16* __restrict__ p = W + f0*INNER + cg8;
  float4 a0 = make_float4(0.f,0.f,0.f,0.f), a1 = a0;
#pragma unroll
  for(int k=0;k<16;k++){
    H8 wv; wv.u = *(const uint4*)(p + k*INNER);
    float x = xin[f0+k];
    a0.x=fmaf(x,(float)wv.h[0],a0.x); a0.y=fmaf(x,(float)wv.h[1],a0.y);
    a0.z=fmaf(x,(float)wv.h[2],a0.z); a0.w=fmaf(x,(float)wv.h[3],a0.w);
    a1.x=fmaf(x,(float)wv.h[4],a1.x); a1.y=fmaf(x,(float)wv.h[5],a1.y);
    a1.z=fmaf(x,(float)wv.h[6],a1.z); a1.w=fmaf(x,(float)wv.h[7],a1.w);
  }
  *(float4*)(SC + fg*INNER + cg8)     = a0;
  *(float4*)(SC + fg*INNER + cg8 + 4) = a1;
}
// a[512] @ W[512][128]h -> SC[fg*128+c], fg in [0,32)
__device__ __forceinline__ void mvp512_128h(const float* __restrict__ ain,
                                            const f16* __restrict__ W,
                                            float* __restrict__ SC, int t){
  const int cg8 = (t&15)<<3, fg = t>>4, f0 = fg<<4;
  const f16* __restrict__ p = W + f0*DIM + cg8;
  float4 a0 = make_float4(0.f,0.f,0.f,0.f), a1 = a0;
#pragma unroll
  for(int k=0;k<16;k++){
    H8 wv; wv.u = *(const uint4*)(p + k*DIM);
    float x = ain[f0+k];
    a0.x=fmaf(x,(float)wv.h[0],a0.x); a0.y=fmaf(x,(float)wv.h[1],a0.y);
    a0.z=fmaf(x,(float)wv.h[2],a0.z); a0.w=fmaf(x,(float)wv.h[3],a0.w);
    a1.x=fmaf(x,(float)wv.h[4],a1.x); a1.y=fmaf(x,(float)wv.h[5],a1.y);
    a1.z=fmaf(x,(float)wv.h[6],a1.z); a1.w=fmaf(x,(float)wv.h[7],a1.w);
  }
  *(float4*)(SC + fg*DIM + cg8)     = a0;
  *(float4*)(SC + fg*DIM + cg8 + 4) = a1;
}
// fp32: x[128] @ W[128][512] -> SC[fq*512+c], fq in [0,4)
__device__ __forceinline__ void mvp128_512f(const float* __restrict__ xin,
                                            const float* __restrict__ W,
                                            float* __restrict__ SC, int t){
  const int cg4 = (t&127)<<2, fq = t>>7;
  float4 acc = make_float4(0.f,0.f,0.f,0.f);
#pragma unroll 8
  for(int f=fq*32; f<fq*32+32; f++){
    float4 wv = *(const float4*)(W + f*INNER + cg4);
    float xv = xin[f];
    FMA4(acc, xv, wv);
  }
  *(float4*)(SC + fq*INNER + cg4) = acc;
}
// fp32: x[128] @ W[128][1024] -> SC[rh*1024+c], rh in [0,2)
__device__ __forceinline__ void mvp128_1024(const float* __restrict__ xin,
                                            const float* __restrict__ W,
                                            float* __restrict__ SC, int t){
  const int cg4 = (t&255)<<2, rh = t>>8;
  float4 acc = make_float4(0.f,0.f,0.f,0.f);
#pragma unroll 8
  for(int f=rh*64; f<rh*64+64; f++){
    float4 wv = *(const float4*)(W + f*(2*INNER) + cg4);
    float xv = xin[f];
    FMA4(acc, xv, wv);
  }
  *(float4*)(SC + rh*(2*INNER) + cg4) = acc;
}

// LN1 output xs[128] (LDS) -> q/k/v for row i. Wq fp16, Wkv fp32, K/V fp32 out.
// SC: 6144 floats. 1 barrier inside.
__device__ __forceinline__ void qkv_tail(const float* __restrict__ xs, int i,
    const f16* __restrict__ Wqh, const float* __restrict__ bq,
    const float* __restrict__ Wkv, const float* __restrict__ bkv,
    const float* __restrict__ be, float* qgn, float* kTn, float* vgn,
    float* __restrict__ SC, int t){
  mvp128_512h(xs, Wqh, SC,        t);   // SC[0..4096)
  mvp128_1024(xs, Wkv, SC + 4096, t);   // SC[4096..6144)
  __syncthreads();
  {
    float s = bq[t];
#pragma unroll
    for(int fg=0; fg<8; fg++) s += SC[fg*INNER + t];
    qgn[i*INNER + t] = s;
  }
#pragma unroll
  for(int cc=0; cc<2; cc++){
    int c = t + cc*512;
    float sv = bkv[c] + SC[4096 + c] + SC[4096 + 1024 + c];
    if(c < INNER) kTn[c*NN + i]            = sv + be[c];
    else          vgn[i*INNER + c - INNER] = sv + be[c-INNER];
  }
}

// fp32-Wq variant for layer 0 (breaks prep->qkv0 dependency). SC: 4096 floats.
__device__ __forceinline__ void qkv_tail0f(const float* __restrict__ xs, int i,
    const float* __restrict__ Wq, const float* __restrict__ bq,
    const float* __restrict__ Wkv, const float* __restrict__ bkv,
    const float* __restrict__ be, float* qgn, float* kTn, float* vgn,
    float* __restrict__ SC, int t){
  mvp128_512f(xs, Wq,  SC,        t);   // SC[0..2048)
  mvp128_1024(xs, Wkv, SC + 2048, t);   // SC[2048..4096)
  __syncthreads();
  qgn[i*INNER + t] = bq[t] + SC[t] + SC[512+t] + SC[1024+t] + SC[1536+t];
#pragma unroll
  for(int cc=0; cc<2; cc++){
    int c = t + cc*512;
    float sv = bkv[c] + SC[2048 + c] + SC[2048 + 1024 + c];
    if(c < INNER) kTn[c*NN + i]            = sv + be[c];
    else          vgn[i*INNER + c - INNER] = sv + be[c-INNER];
  }
}

// ---- fused init kernel, grid 800:
//   blocks 0..255   : node-init + LN1 + layer-0 QKV (fp32 weights)
//   blocks 256..287 : layer-invariant edge planes -> ebg
//   blocks 288..799 : fp32->fp16 weight conversion (+ flag zero on block 288)
__global__ __launch_bounds__(512) void k_init(const float* atom_emb, const float* noise,
    float* nodes, const float* ln1_g, const float* ln1_b,
    const float* Wq, const float* bq, const float* Wkv, const float* bkv, const float* be,
    float* qg, float* kT, float* vg,
    const int* bonds, const float* coords, float* ebg,
    const float* Wo, const float* W1, const float* W2,
    f16* Wqh, f16* Woh, f16* W1h, f16* W2h, int* cnt){
  __shared__ __align__(16) float SC[6144];
  __shared__ __align__(16) float xsm[DIM];
  __shared__ __align__(16) float ebs[8*768];
  const int t = threadIdx.x, bid = blockIdx.x;
  if(bid >= 288){
    // weight conversion: 4 arrays x 393216 elements = 1572864; 512 blocks
    if(bid == 288 && t < DEPTH*32) cnt[t] = 0;
    const int NQ = DEPTH*DIM*INNER;
    for(int k = (bid-288)*512 + t; k < 4*NQ; k += 512*512){
      float v; f16* dst;
      if(k < NQ)        { v = Wq[k];        dst = Wqh + k; }
      else if(k < 2*NQ) { v = Wo[k-NQ];     dst = Woh + (k-NQ); }
      else if(k < 3*NQ) { v = W1[k-2*NQ];   dst = W1h + (k-2*NQ); }
      else              { v = W2[k-3*NQ];   dst = W2h + (k-3*NQ); }
      *dst = (f16)v;
    }
    return;
  }
  if(bid >= NN){
    const int i0 = (bid-NN)<<3;
#pragma unroll
    for(int cc=0; cc<12; cc++) ebs[cc*512 + t] = 0.f;
    __syncthreads();
    {
      const int bi = bonds[2*t], bj = bonds[2*t+1];
      const bool hi = (bi>=i0 && bi<i0+8), hj = (bj>=i0 && bj<i0+8);
      if(hi || hj){
        float dx = coords[3*bi+0] - coords[3*bj+0];
        float dy = coords[3*bi+1] - coords[3*bj+1];
        float dz = coords[3*bi+2] - coords[3*bj+2];
        if(hi){ float* e = ebs + (bi-i0)*768; e[bj]=dx;  e[256+bj]=dy;  e[512+bj]=dz;  }
        if(hj){ float* e = ebs + (bj-i0)*768; e[bi]=-dx; e[256+bi]=-dy; e[512+bi]=-dz; }
      }
    }
    __syncthreads();
#pragma unroll
    for(int cc=0; cc<12; cc++) ebg[(size_t)i0*768 + cc*512 + t] = ebs[cc*512 + t];
    return;
  }
  const int i = bid, w = t>>6, l = t&63;
  float nd0 = (l<NF)?    atom_emb[i*NF + l]      : noise[0];
  float nd1 = (64+l<NF)? atom_emb[i*NF + 64 + l] : noise[0];
  if(w==0){ nodes[i*DIM + l] = nd0; nodes[i*DIM + 64 + l] = nd1; }
  float x0, x1;
  ln_wave(nd0, nd1, ln1_g, ln1_b, l, x0, x1);
  xsm[l] = x0; xsm[64+l] = x1;     // all waves write identical values (benign)
  __syncthreads();
  qkv_tail0f(xsm, i, Wq, bq, Wkv, bkv, be, qg, kT, vg, SC, t);
}

// ======== fused attn+layer kernel, grid 512 ========
// blocks 0..255  : attn role (h=bid>>5, tile=bid&31). 138KB LDS -> 1 block/CU,
//                  so all 256 attn blocks dispatch first (IDs 0..255) and fill
//                  all CUs; layer blocks start only as attn blocks retire.
// blocks 256..511: layer role (row i=bid-256); waits on cnt[tile(i)]==8.
__global__ __launch_bounds__(512) void k_al(
    const float* __restrict__ qg, const float* __restrict__ kT,
    const float* __restrict__ vg, const float* __restrict__ ebg,
    const float* __restrict__ We, float* __restrict__ aog,
    float* nodes,
    float* qg_n, float* kT_n, float* vg_n,
    const f16* __restrict__ Woh, const float* __restrict__ bo,
    const float* __restrict__ Wg1,
    const float* __restrict__ ln2_g, const float* __restrict__ ln2_b,
    const f16* __restrict__ W1h, const float* __restrict__ b1,
    const f16* __restrict__ W2h, const float* __restrict__ b2,
    const float* __restrict__ Wg2,
    const float* __restrict__ ln1_g_n, const float* __restrict__ ln1_b_n,
    const f16* __restrict__ Wqh_n, const float* __restrict__ bq_n,
    const float* __restrict__ Wkv_n, const float* __restrict__ bkv_n,
    const float* __restrict__ be_n,
    const float* __restrict__ out_w, const float* __restrict__ out_b,
    float* eout, int* cnt_l, int has_next)
{
  __shared__ __align__(16) float smem[35328];   // 141312 B, role-dependent layout
  const int t = threadIdx.x, bid = blockIdx.x;

  if(bid < NN){
    // ================= ATTN ROLE =================
    float* kTs = smem;            // [64][256]
    float* vs  = smem + 16384;    // [256][64]
    float* aW  = smem + 32768;    // [8][256]
    float* qsm = smem + 34816;    // [8][64]
    const int h = bid >> 5, i0 = (bid & 31) << 3;
    const int w = t>>6, l = t&63;
    const int qb = h*DH, j0 = l<<2;

    // stage K slice (contiguous 64KB) + V slice (strided) + q
    {
      const float* kbase = kT + qb*NN;
#pragma unroll
      for(int r=0;r<8;r++){
        int idx = r*2048 + (t<<2);
        *(float4*)(kTs + idx) = *(const float4*)(kbase + idx);
      }
      const int jr = t>>4, c4 = (t&15)<<2;
#pragma unroll
      for(int p=0;p<8;p++){
        int j = p*32 + jr;
        *(float4*)(vs + j*64 + c4) = *(const float4*)(vg + j*INNER + qb + c4);
      }
    }
    qsm[w*DH + l] = qg[(i0+w)*INNER + qb + l];

    // L2 warm for this layer's weight streams (XCD-sliced)
    {
      const int s = bid >> 3;
      unsigned keep = 0u;
      if(t < 256){
        keep ^= ((const uint4*)((const char*)Woh   + (size_t)s*4096))[t].x;
        keep ^= ((const uint4*)((const char*)W1h   + (size_t)s*4096))[t].y;
        keep ^= ((const uint4*)((const char*)W2h   + (size_t)s*4096))[t].z;
        if(has_next)
          keep ^= ((const uint4*)((const char*)Wqh_n + (size_t)s*4096))[t].w;
      }
      if(has_next){
        keep ^= ((const uint4*)((const char*)Wkv_n + (size_t)s*16384))[t].x;
        keep ^= ((const uint4*)((const char*)Wkv_n + (size_t)s*16384))[512 + t].x;
      }
      asm volatile("" :: "v"(keep));
    }
    __syncthreads();

    // qwe_c = q_row . We[c, h-slice]
    float qwe0, qwe1, qwe2;
    {
      float qv = qsm[w*DH + l];
      qwe0 = qv*We[0*INNER + qb + l];
      qwe1 = qv*We[1*INNER + qb + l];
      qwe2 = qv*We[2*INNER + qb + l];
#pragma unroll
      for(int o=32;o;o>>=1){
        qwe0 += __shfl_xor(qwe0,o); qwe1 += __shfl_xor(qwe1,o); qwe2 += __shfl_xor(qwe2,o);
      }
    }
    float s0=0.f,s1=0.f,s2=0.f,s3=0.f;
#pragma unroll 8
    for(int o=0;o<DH;o++){
      float qv = qsm[w*DH + o];
      float4 kk = *(const float4*)(kTs + o*NN + j0);
      s0=fmaf(qv,kk.x,s0); s1=fmaf(qv,kk.y,s1); s2=fmaf(qv,kk.z,s2); s3=fmaf(qv,kk.w,s3);
    }
    const float* __restrict__ e = ebg + (size_t)(i0+w)*768;
    float4 ex = *(const float4*)(e + j0);
    float4 ey = *(const float4*)(e + 256 + j0);
    float4 ez = *(const float4*)(e + 512 + j0);
    s0 = (s0 + qwe0*ex.x + qwe1*ey.x + qwe2*ez.x)*ATTN_SCALE;
    s1 = (s1 + qwe0*ex.y + qwe1*ey.y + qwe2*ez.y)*ATTN_SCALE;
    s2 = (s2 + qwe0*ex.z + qwe1*ey.z + qwe2*ez.z)*ATTN_SCALE;
    s3 = (s3 + qwe0*ex.w + qwe1*ey.w + qwe2*ez.w)*ATTN_SCALE;
    float mx = wred_max(fmaxf(fmaxf(s0,s1),fmaxf(s2,s3)));
    float p0=expf(s0-mx), p1=expf(s1-mx), p2=expf(s2-mx), p3=expf(s3-mx);
    float inv = 1.f / wred_sum(p0+p1+p2+p3);
    float a0=p0*inv, a1=p1*inv, a2=p2*inv, a3=p3*inv;
    *(float4*)(aW + w*NN + j0) = make_float4(a0,a1,a2,a3);
    float c0 = a0*ex.x + a1*ex.y + a2*ex.z + a3*ex.w;
    float c1 = a0*ey.x + a1*ey.y + a2*ey.z + a3*ey.w;
    float c2 = a0*ez.x + a1*ez.y + a2*ez.z + a3*ez.w;
    c0 = wred_sum(c0); c1 = wred_sum(c1); c2 = wred_sum(c2);
    __builtin_amdgcn_wave_barrier();   // order aW writes before same-wave aW reads
    // PV: lane l owns output dim qb+l; aW broadcast, vs 2-way-free
    const float* aww = aW + w*NN;
    float acc0 = 0.f, acc1 = 0.f;
#pragma unroll 8
    for(int j=0;j<NN;j+=2){
      acc0 = fmaf(aww[j],   vs[j*64 + l],     acc0);
      acc1 = fmaf(aww[j+1], vs[(j+1)*64 + l], acc1);
    }
    float ov = acc0 + acc1
             + c0*We[0*INNER + qb + l]
             + c1*We[1*INNER + qb + l]
             + c2*We[2*INNER + qb + l];
    aog[(i0+w)*INNER + qb + l] = ov;
    __syncthreads();                   // all aog stores issued (vmcnt drained per-wave)
    if(t==0){
      __threadfence();                 // writeback to coherence point
      atomicAdd(cnt_l + (bid & 31), 1);
    }
    return;
  }

  // ================= LAYER ROLE =================
  float* SC  = smem;            // 6144
  float* qs  = smem + 6144;     // 512
  float* aos = smem + 6656;     // 512
  float* xsm = smem + 7168;     // 128
  const int i = bid - NN;
  const int w = t>>6, l = t&63;

  float nd0 = nodes[i*DIM + l];        // per-wave redundant row state
  float nd1 = nodes[i*DIM + 64 + l];

  // wait for this row-tile's 8 attn producers
  if(t==0){
    while(atomicAdd(cnt_l + (i>>3), 0) < 8){ __builtin_amdgcn_s_sleep(2); }
    __threadfence();                   // invalidate: see producers' aog
  }
  __syncthreads();
  aos[t] = aog[i*INNER + t];
  __syncthreads();                               // B1

  // ---- Wo (fp16) + gate1 + LN2 ----
  mvp512_128h(aos, Woh, SC, t);
  __syncthreads();                               // B2
  {
    float o0 = bo[l], o1 = bo[64+l];
#pragma unroll
    for(int fg=0; fg<32; fg++){ o0 += SC[fg*DIM + l]; o1 += SC[fg*DIM + 64 + l]; }
    gate_wave(o0, o1, nd0, nd1, Wg1, l);
    float x0, x1;
    ln_wave(nd0, nd1, ln2_g, ln2_b, l, x0, x1);
    xsm[l] = x0; xsm[64+l] = x1;
  }
  __syncthreads();                               // B3 (xsm ready; SC free)

  // ---- FFN (fp16) ----
  mvp128_512h(xsm, W1h, SC, t);
  __syncthreads();                               // B4
  {
    float a = b1[t];
#pragma unroll
    for(int fg=0; fg<8; fg++) a += SC[fg*INNER + t];
    qs[t] = 0.5f*a*(1.f + erff(a*0.70710678118654752440f));
  }
  __syncthreads();                               // B5 (hidden ready; SC free)
  mvp512_128h(qs, W2h, SC, t);
  __syncthreads();                               // B6
  {
    float y0 = b2[l], y1 = b2[64+l];
#pragma unroll
    for(int fg=0; fg<32; fg++){ y0 += SC[fg*DIM + l]; y1 += SC[fg*DIM + 64 + l]; }
    gate_wave(y0, y1, nd0, nd1, Wg2, l);
    if(w==0){ nodes[i*DIM + l] = nd0; nodes[i*DIM + 64 + l] = nd1; }
    if(has_next){
      float x0, x1;
      ln_wave(nd0, nd1, ln1_g_n, ln1_b_n, l, x0, x1);
      xsm[l] = x0; xsm[64+l] = x1;
    } else if(w==0){
      float ev = nd0*out_w[l] + nd1*out_w[64+l];
      ev = wred_sum(ev);
      if(l==0) eout[i] = ev + out_b[0];
    }
  }
  if(has_next){
    __syncthreads();                             // B7 (xsm ready; SC free)
    qkv_tail(xsm, i, Wqh_n, bq_n, Wkv_n, bkv_n, be_n,
             qg_n, kT_n, vg_n, SC, t);           // B8
  }
}

extern "C" void kernel_launch(void* const* d_in, const int* in_sizes, int n_in,
                              void* d_out, int out_size, void* d_ws, size_t ws_size,
                              hipStream_t stream){
  const float* coords   = (const float*)d_in[0];
  const int*   bonds    = (const int*  )d_in[1];
  const float* noise    = (const float*)d_in[2];
  const float* atom_emb = (const float*)d_in[3];
  const float* ln1_g = (const float*)d_in[4];
  const float* ln1_b = (const float*)d_in[5];
  const float* Wq    = (const float*)d_in[6];
  const float* bq    = (const float*)d_in[7];
  const float* Wkv   = (const float*)d_in[8];
  const float* bkv   = (const float*)d_in[9];
  const float* We    = (const float*)d_in[10];
  const float* be    = (const float*)d_in[11];
  const float* Wo    = (const float*)d_in[12];
  const float* bo    = (const float*)d_in[13];
  const float* Wg1   = (const float*)d_in[14];
  const float* ln2_g = (const float*)d_in[15];
  const float* ln2_b = (const float*)d_in[16];
  const float* W1    = (const float*)d_in[17];
  const float* b1    = (const float*)d_in[18];
  const float* W2    = (const float*)d_in[19];
  const float* b2    = (const float*)d_in[20];
  const float* Wg2   = (const float*)d_in[21];
  const float* out_w = (const float*)d_in[22];
  const float* out_b = (const float*)d_in[23];

  // workspace carve (bytes); total ~7.5 MB
  char* base = (char*)d_ws;
  float* nodes = (float*)(base);                    // 131072 B
  float* qb0   = (float*)(base + 131072);           // 524288 B
  float* qb1   = (float*)(base + 655360);
  float* aog   = (float*)(base + 1179648);
  float* ebg   = (float*)(base + 1703936);          // 786432 B
  float* kb0   = (float*)(base + 2490368);          // 524288 B
  float* kb1   = (float*)(base + 3014656);
  float* vb0   = (float*)(base + 3538944);
  float* vb1   = (float*)(base + 4063232);
  f16*   Wqh   = (f16*  )(base + 4587520);          // 786432 B
  f16*   Woh   = (f16*  )(base + 5373952);
  f16*   W1h   = (f16*  )(base + 6160384);
  f16*   W2h   = (f16*  )(base + 6946816);
  int*   cnt   = (int*  )(base + 7733248);          // 6*32 ints
  float* eout  = (float*)d_out;

  k_init<<<800, 512, 0, stream>>>(atom_emb, noise, nodes, ln1_g, ln1_b,
                                  Wq, bq, Wkv, bkv, be,
                                  qb0, kb0, vb0,
                                  bonds, coords, ebg,
                                  Wo, W1, W2, Wqh, Woh, W1h, W2h, cnt);
  for(int l=0; l<DEPTH; l++){
    int has_next = (l < DEPTH-1);
    int ln = has_next ? l+1 : l;    // keep pointers valid when unused
    float* qcur = (l&1)? qb1:qb0;  float* kcur = (l&1)? kb1:kb0;  float* vcur = (l&1)? vb1:vb0;
    float* qnxt = (l&1)? qb0:qb1;  float* knxt = (l&1)? kb0:kb1;  float* vnxt = (l&1)? vb0:vb1;
    const f16* Woh_l  = Woh + (size_t)l*INNER*DIM;
    const f16* W1h_l  = W1h + (size_t)l*DIM*4*DIM;
    const f16* W2h_l  = W2h + (size_t)l*4*DIM*DIM;
    const f16* Wqh_n  = Wqh + (size_t)ln*DIM*INNER;
    const float* Wkv_n = Wkv + (size_t)ln*DIM*2*INNER;
    k_al<<<2*NN, 512, 0, stream>>>(
      qcur, kcur, vcur, ebg,
      We + (size_t)l*3*INNER, aog,
      nodes,
      qnxt, knxt, vnxt,
      Woh_l, bo + (size_t)l*DIM, Wg1 + (size_t)l*3*DIM,
      ln2_g + (size_t)l*DIM, ln2_b + (size_t)l*DIM,
      W1h_l, b1 + (size_t)l*4*DIM,
      W2h_l, b2 + (size_t)l*DIM, Wg2 + (size_t)l*3*DIM,
      ln1_g + (size_t)ln*DIM, ln1_b + (size_t)ln*DIM,
      Wqh_n, bq + (size_t)ln*INNER,
      Wkv_n, bkv + (size_t)ln*2*INNER,
      be  + (size_t)ln*INNER,
      out_w, out_b, eout, cnt + l*32, has_next);
  }
}